// Round 3
// baseline (176.385 us; speedup 1.0000x reference)
//
#include <hip/hip_runtime.h>

// FeaturesLinear: out[b,:] = sum_{h<50} user_W[fid[b,h]] * rating_W[ridx[b,h]]
//                            + item_W[item_ids[b]] + bias
// B=16384, HIST=50, D=128. Segments contiguous (repeat(arange(B), 50)).
//
// R1: 62us, 3.3 TB/s EA, occupancy 51%, latency/queue-bound.
// R2: explicit x5 unroll neutral -> compiler already unrolled. Occupancy is
//     the remaining suspect (8 blocks/CU exactly, no replenishment pool).
// R3: drop LDS entirely (rating_W is L1-resident; ids via broadcast loads),
//     BLOCK=128 (2 waves), grid=4096 -> fine-grained blocks, no barrier,
//     LDS=0 -> better CU balance + replenishment.

#define BATCH   16384
#define HIST    50
#define DIM4    32            // 128 floats = 32 float4
#define BLOCK   128           // 2 waves; each wave covers 2 batch rows
#define ROWS_PER_BLOCK 4

__global__ __launch_bounds__(BLOCK) void features_linear_kernel(
    const int*    __restrict__ feature_ids,   // [TOTAL]
    const float*  __restrict__ ratings,       // [TOTAL]
    const int*    __restrict__ item_ids,      // [BATCH]
    const float4* __restrict__ user_W,        // [100001, 32] as float4
    const float4* __restrict__ rating_W,      // [10, 32] as float4
    const float4* __restrict__ item_W,        // [100000, 32] as float4
    const float4* __restrict__ bias,          // [32] as float4
    float4*       __restrict__ out)           // [BATCH, 32] as float4
{
    const int tid  = threadIdx.x;
    const int wave = tid >> 6;        // 0..1
    const int lane = tid & 63;
    const int half = lane >> 5;       // 0..1: which batch row within the wave
    const int d4   = lane & 31;       // float4 index within the 128-dim row

    const int b   = blockIdx.x * ROWS_PER_BLOCK + wave * 2 + half;
    const int off = b * HIST;

    // Prefetch epilogue loads early so they overlap the gather loop.
    const int    iid = item_ids[b];
    const float4 iw  = item_W[iid * DIM4 + d4];
    const float4 bs  = bias[d4];

    float4 acc; acc.x = 0.f; acc.y = 0.f; acc.z = 0.f; acc.w = 0.f;

#pragma unroll 5
    for (int h = 0; h < HIST; ++h) {
        // Broadcast loads: all 32 lanes of the half-wave read one address
        // (single cache line, L1/L2 served after first touch).
        const int   fid  = feature_ids[off + h];
        const float r    = ratings[off + h];
        // ratings are exact multiples of 0.5 in [0.5,5.0]; r*2 is an exact
        // integer in [1,10] -> index r*2-1 in [0,9]. Exact, no fp edge.
        const int   ridx = (int)(r * 2.0f) - 1;

        const float4 u  = user_W[fid * DIM4 + d4];    // 512B coalesced row
        const float4 rw = rating_W[ridx * DIM4 + d4]; // 5KB table, L1-hot

        acc.x += u.x * rw.x;
        acc.y += u.y * rw.y;
        acc.z += u.z * rw.z;
        acc.w += u.w * rw.w;
    }

    float4 o;
    o.x = acc.x + iw.x + bs.x;
    o.y = acc.y + iw.y + bs.y;
    o.z = acc.z + iw.z + bs.z;
    o.w = acc.w + iw.w + bs.w;
    out[b * DIM4 + d4] = o;
}

extern "C" void kernel_launch(void* const* d_in, const int* in_sizes, int n_in,
                              void* d_out, int out_size, void* d_ws, size_t ws_size,
                              hipStream_t stream) {
    const int*    feature_ids = (const int*)   d_in[0];
    const float*  ratings     = (const float*) d_in[1];
    // d_in[2] = segment_ids: unused (segments are contiguous by construction)
    const int*    item_ids    = (const int*)   d_in[3];
    const float4* user_W      = (const float4*)d_in[4];
    const float4* rating_W    = (const float4*)d_in[5];
    const float4* item_W      = (const float4*)d_in[6];
    const float4* bias        = (const float4*)d_in[7];
    float4*       out         = (float4*)      d_out;

    dim3 grid(BATCH / ROWS_PER_BLOCK);   // 4096 blocks
    dim3 block(BLOCK);
    features_linear_kernel<<<grid, block, 0, stream>>>(
        feature_ids, ratings, item_ids, user_W, rating_W, item_W, bias, out);
}